// Round 4
// baseline (365.556 us; speedup 1.0000x reference)
//
#include <hip/hip_runtime.h>

#define NN 6144
#define DD 768
#define NB 48               // 6144 / 128 tile blocks per dim
#define NTILES 1176         // NB*(NB+1)/2 upper-triangular tiles
#define INV_T 14.285714285714286f
#define CMAX  14.285714285714286f

typedef int i32x4 __attribute__((ext_vector_type(4)));
typedef int i32x8 __attribute__((ext_vector_type(8)));
typedef float f32x4_t __attribute__((ext_vector_type(4)));

__device__ __forceinline__ void load_lds16(const void* g, void* l) {
    __builtin_amdgcn_global_load_lds((__attribute__((address_space(1))) void*)g,
                                     (__attribute__((address_space(3))) void*)l,
                                     16, 0, 0);
}

// Kernel 1: L2-normalize rows -> fp8 e4m3 (unit MX scale); zero den/num sums
// and the completion counter. One wave per row; 1536 blocks x 256 threads.
__global__ void norm_kernel(const float* __restrict__ feats,
                            unsigned int* __restrict__ fb8,   // 6144*192 uints
                            float* __restrict__ den_num) {    // [0..NN)=den, [NN..2NN)=num, [2NN]=counter
    const int wid = threadIdx.x >> 6;
    const int lane = threadIdx.x & 63;
    const int row = blockIdx.x * 4 + wid;

    if (threadIdx.x < 8) den_num[blockIdx.x * 8 + threadIdx.x] = 0.0f;
    if (blockIdx.x == 0 && threadIdx.x == 8) ((int*)(den_num + 2 * NN))[0] = 0;

    const float4* src = (const float4*)(feats + (size_t)row * DD);
    float4 v[3];
    float ss = 0.0f;
#pragma unroll
    for (int i = 0; i < 3; ++i) {
        v[i] = src[lane + i * 64];
        ss += v[i].x * v[i].x + v[i].y * v[i].y + v[i].z * v[i].z + v[i].w * v[i].w;
    }
#pragma unroll
    for (int m = 32; m >= 1; m >>= 1) ss += __shfl_xor(ss, m);
    const float sc = 1.0f / fmaxf(sqrtf(ss), 1e-12f);

#pragma unroll
    for (int i = 0; i < 3; ++i) {
        unsigned int w = 0;
        w = __builtin_amdgcn_cvt_pk_fp8_f32(v[i].x * sc, v[i].y * sc, w, 0);
        w = __builtin_amdgcn_cvt_pk_fp8_f32(v[i].z * sc, v[i].w * sc, w, 1);
        fb8[(size_t)row * 192 + lane + i * 64] = w;
    }
}

// Kernel 2: upper-triangular MX-fp8 MFMA Gram tiles + fused exp row/col sums
// into den_sum (all) and num_sum (positive pairs). Last block to finish
// computes the final loss (device-scope counter + agent-scope loads).
// 1176 blocks (one 128x128 tile), 256 threads (2x2 waves of 64x64).
// __launch_bounds__(256,2): 256 VGPR/thread — r3's (256,4) cap spilled af[]
// to scratch (497MB FETCH / 344MB WRITE). Occupancy was 2 blocks/CU anyway.
__global__ __launch_bounds__(256, 2) void gemm_expsum_kernel(
        const unsigned char* __restrict__ fb8,
        float* __restrict__ den_sum, float* __restrict__ num_sum,
        int* __restrict__ counter, float* __restrict__ out) {
    __shared__ __align__(16) char sA[128 * 128];
    __shared__ __align__(16) char sB[128 * 128];

    // triangular index -> (bi, bj), bi <= bj
    int rem = blockIdx.x;
    int bi = 0, rowlen = NB;
    while (rem >= rowlen) { rem -= rowlen; rowlen--; bi++; }
    const int bj = bi + rem;
    const bool isdiag = (bi == bj);
    const bool neardiag = (bj - bi) <= 1;
    const int i0 = bi * 128;
    const int j0 = bj * 128;

    const int t = threadIdx.x;
    const int lane = t & 63;
    const int wid = t >> 6;
    const int wm = wid >> 1;  // wave row (0..1)
    const int wn = wid & 1;   // wave col (0..1)

    // staging: thread t -> row = t>>3 (+32/issue), 16B chunk (t&7)^(row&7)
    const int srow = t >> 3;
    const int scb = ((t & 7) ^ (srow & 7)) * 16;
    const unsigned char* gA = fb8 + (size_t)(i0 + srow) * DD + scb;
    const unsigned char* gB = fb8 + (size_t)(j0 + srow) * DD + scb;
    char* ldsA = sA + wid * 1024;  // wave-uniform base; HW adds lane*16
    char* ldsB = sB + wid * 1024;

    f32x4_t acc[4][4];
    const f32x4_t zz = {0.0f, 0.0f, 0.0f, 0.0f};
#pragma unroll
    for (int mi = 0; mi < 4; ++mi)
#pragma unroll
        for (int ni = 0; ni < 4; ++ni) acc[mi][ni] = zz;

    const int q = lane >> 4;
    const int mrow = lane & 15;
    const int x7 = lane & 7;
    const int c0 = ((q << 1) ^ x7) << 4;        // chunk byte offset, k-half 0
    const int c1 = (((q << 1) | 1) ^ x7) << 4;  // k-half 1

    for (int kb = 0; kb < 6; ++kb) {
        const int k0 = kb * 128;
#pragma unroll
        for (int i = 0; i < 4; ++i) {
            load_lds16(gA + (size_t)(i * 32) * DD + k0, ldsA + i * 4096);
            load_lds16(gB + (size_t)(i * 32) * DD + k0, ldsB + i * 4096);
        }
        __syncthreads();

        i32x8 af[4];
#pragma unroll
        for (int mi = 0; mi < 4; ++mi) {
            const char* p = sA + (wm * 64 + mi * 16 + mrow) * 128;
            i32x4 lo = *(const i32x4*)(p + c0);
            i32x4 hi = *(const i32x4*)(p + c1);
            af[mi] = __builtin_shufflevector(lo, hi, 0, 1, 2, 3, 4, 5, 6, 7);
        }
#pragma unroll
        for (int ni = 0; ni < 4; ++ni) {
            const char* p = sB + (wn * 64 + ni * 16 + mrow) * 128;
            i32x4 lo = *(const i32x4*)(p + c0);
            i32x4 hi = *(const i32x4*)(p + c1);
            i32x8 bf = __builtin_shufflevector(lo, hi, 0, 1, 2, 3, 4, 5, 6, 7);
#pragma unroll
            for (int mi = 0; mi < 4; ++mi)
                acc[mi][ni] = __builtin_amdgcn_mfma_scale_f32_16x16x128_f8f6f4(
                    af[mi], bf, acc[mi][ni], 0, 0,
                    0, 0x7F7F7F7F, 0, 0x7F7F7F7F);  // unit scales (E8M0=127)
        }
        __syncthreads();
    }

    // Epilogue. C/D layout: col=lane&15 (+ni*16), row=(lane>>4)*4+reg (+mi*16).
    const int colb = j0 + wn * 64 + mrow;
    const int rowb = i0 + wm * 64 + (q << 2);
    float cs[4] = {0.f, 0.f, 0.f, 0.f};
    float csn[4] = {0.f, 0.f, 0.f, 0.f};
#pragma unroll
    for (int mi = 0; mi < 4; ++mi) {
        float rsv[4] = {0.f, 0.f, 0.f, 0.f};
        float rsn[4] = {0.f, 0.f, 0.f, 0.f};
#pragma unroll
        for (int ni = 0; ni < 4; ++ni) {
            const int col = colb + ni * 16;
#pragma unroll
            for (int r = 0; r < 4; ++r) {
                const int row = rowb + mi * 16 + r;
                const float v = acc[mi][ni][r] * INV_T;
                float e = __expf(v - CMAX);
                if (isdiag && row == col) e = 0.0f;
                rsv[r] += e;
                cs[ni] += e;
                if (neardiag && (row / 3 == col / 3) && row != col) {
                    rsn[r] += e;
                    csn[ni] += e;
                }
            }
        }
#pragma unroll
        for (int r = 0; r < 4; ++r) {
            float v = rsv[r];
            v += __shfl_xor(v, 8);
            v += __shfl_xor(v, 4);
            v += __shfl_xor(v, 2);
            v += __shfl_xor(v, 1);
            if (mrow == 0) atomicAdd(&den_sum[rowb + mi * 16 + r], v);
        }
        if (neardiag) {
#pragma unroll
            for (int r = 0; r < 4; ++r) {
                float v = rsn[r];
                v += __shfl_xor(v, 8);
                v += __shfl_xor(v, 4);
                v += __shfl_xor(v, 2);
                v += __shfl_xor(v, 1);
                if (mrow == 0) atomicAdd(&num_sum[rowb + mi * 16 + r], v);
            }
        }
    }
    if (!isdiag) {
#pragma unroll
        for (int ni = 0; ni < 4; ++ni) {
            float v = cs[ni];
            v += __shfl_xor(v, 16);
            v += __shfl_xor(v, 32);
            if (q == 0) atomicAdd(&den_sum[colb + ni * 16], v);
        }
        if (neardiag) {
#pragma unroll
            for (int ni = 0; ni < 4; ++ni) {
                float v = csn[ni];
                v += __shfl_xor(v, 16);
                v += __shfl_xor(v, 32);
                if (q == 0) atomicAdd(&num_sum[colb + ni * 16], v);
            }
        }
    }

    // Last block computes the loss. Standard threadfence-reduction pattern:
    // per-thread device fence, block barrier, counter RMW (acq_rel, agent);
    // the last block reads den/num with agent-scope atomic loads (XCD-safe).
    __threadfence();
    __syncthreads();
    __shared__ int lastflag;
    if (t == 0) {
        const int prev = __hip_atomic_fetch_add(counter, 1, __ATOMIC_ACQ_REL,
                                                __HIP_MEMORY_SCOPE_AGENT);
        lastflag = (prev == NTILES - 1) ? 1 : 0;
    }
    __syncthreads();
    if (lastflag) {
        float local = 0.0f;
        for (int i = t; i < NN; i += 256) {
            const float d = __hip_atomic_load(&den_sum[i], __ATOMIC_RELAXED,
                                              __HIP_MEMORY_SCOPE_AGENT);
            const float n = __hip_atomic_load(&num_sum[i], __ATOMIC_RELAXED,
                                              __HIP_MEMORY_SCOPE_AGENT);
            local += logf(d) - logf(n);   // CMAX cancels in den-num
        }
#pragma unroll
        for (int m = 32; m >= 1; m >>= 1) local += __shfl_xor(local, m);
        __shared__ float wsum[4];
        if ((t & 63) == 0) wsum[t >> 6] = local;
        __syncthreads();
        if (t == 0) out[0] = (wsum[0] + wsum[1] + wsum[2] + wsum[3]) / (float)NN;
    }
}

extern "C" void kernel_launch(void* const* d_in, const int* in_sizes, int n_in,
                              void* d_out, int out_size, void* d_ws, size_t ws_size,
                              hipStream_t stream) {
    const float* feats = (const float*)d_in[0];
    float* out = (float*)d_out;

    char* ws = (char*)d_ws;
    unsigned int* fb8 = (unsigned int*)ws;                 // 6144*768 = 4718592 B
    float* den_num    = (float*)(ws + 4718592);            // 2*6144*4 + 4 B
    float* den_sum    = den_num;
    float* num_sum    = den_num + NN;
    int*   counter    = (int*)(den_num + 2 * NN);

    norm_kernel<<<NN / 4, 256, 0, stream>>>(feats, fb8, den_num);
    gemm_expsum_kernel<<<NTILES, 256, 0, stream>>>((const unsigned char*)fb8,
                                                   den_sum, num_sum, counter, out);
}

// Round 5
// 187.613 us; speedup vs baseline: 1.9485x; 1.9485x over previous
//
#include <hip/hip_runtime.h>

#define NN 6144
#define DD 768
#define NB 48               // 6144 / 128 tile blocks per dim
#define NTILES 1176         // NB*(NB+1)/2 upper-triangular tiles
#define INV_T 14.285714285714286f
#define CMAX  14.285714285714286f

typedef int i32x4 __attribute__((ext_vector_type(4)));
typedef int i32x8 __attribute__((ext_vector_type(8)));
typedef float f32x4_t __attribute__((ext_vector_type(4)));

__device__ __forceinline__ void load_lds16(const void* g, void* l) {
    __builtin_amdgcn_global_load_lds((__attribute__((address_space(1))) void*)g,
                                     (__attribute__((address_space(3))) void*)l,
                                     16, 0, 0);
}

// Kernel 1: L2-normalize rows -> fp8 e4m3 (unit MX scale); zero den/num sums
// and the completion counter. One wave per row; 1536 blocks x 256 threads.
__global__ void norm_kernel(const float* __restrict__ feats,
                            unsigned int* __restrict__ fb8,   // 6144*192 uints
                            float* __restrict__ den_num) {    // [0..NN)=den, [NN..2NN)=num, [2NN]=counter
    const int wid = threadIdx.x >> 6;
    const int lane = threadIdx.x & 63;
    const int row = blockIdx.x * 4 + wid;

    if (threadIdx.x < 8) den_num[blockIdx.x * 8 + threadIdx.x] = 0.0f;
    if (blockIdx.x == 0 && threadIdx.x == 8) ((int*)(den_num + 2 * NN))[0] = 0;

    const float4* src = (const float4*)(feats + (size_t)row * DD);
    float4 v[3];
    float ss = 0.0f;
#pragma unroll
    for (int i = 0; i < 3; ++i) {
        v[i] = src[lane + i * 64];
        ss += v[i].x * v[i].x + v[i].y * v[i].y + v[i].z * v[i].z + v[i].w * v[i].w;
    }
#pragma unroll
    for (int m = 32; m >= 1; m >>= 1) ss += __shfl_xor(ss, m);
    const float sc = 1.0f / fmaxf(sqrtf(ss), 1e-12f);

#pragma unroll
    for (int i = 0; i < 3; ++i) {
        unsigned int w = 0;
        w = __builtin_amdgcn_cvt_pk_fp8_f32(v[i].x * sc, v[i].y * sc, w, 0);
        w = __builtin_amdgcn_cvt_pk_fp8_f32(v[i].z * sc, v[i].w * sc, w, 1);
        fb8[(size_t)row * 192 + lane + i * 64] = w;
    }
}

// Kernel 2: upper-triangular MX-fp8 MFMA Gram tiles + fused exp row/col sums
// into den_sum (all) and num_sum (positive pairs). Last block to finish
// computes the final loss (agent-scope counter + agent-scope loads).
// 1176 blocks (one 128x128 tile), 256 threads (2x2 waves of 64x64).
// __launch_bounds__(256,2): 256 regs/thread budget.
// #pragma unroll 1 on the k-loop: r3/r4 spilled 185-344 MB to scratch because
// LLVM fully unrolled the 6-trip loop and interleaved 6 iterations' fragments
// (spill bytes/iter ~= af[] size). One iteration fits in ~140 regs.
__global__ __launch_bounds__(256, 2) void gemm_expsum_kernel(
        const unsigned char* __restrict__ fb8,
        float* __restrict__ den_sum, float* __restrict__ num_sum,
        int* __restrict__ counter, float* __restrict__ out) {
    __shared__ __align__(16) char sA[128 * 128];
    __shared__ __align__(16) char sB[128 * 128];

    // triangular index -> (bi, bj), bi <= bj
    int rem = blockIdx.x;
    int bi = 0, rowlen = NB;
    while (rem >= rowlen) { rem -= rowlen; rowlen--; bi++; }
    const int bj = bi + rem;
    const bool isdiag = (bi == bj);
    const bool neardiag = (bj - bi) <= 1;
    const int i0 = bi * 128;
    const int j0 = bj * 128;

    const int t = threadIdx.x;
    const int lane = t & 63;
    const int wid = t >> 6;
    const int wm = wid >> 1;  // wave row (0..1)
    const int wn = wid & 1;   // wave col (0..1)

    // staging: thread t -> row = t>>3 (+32/issue), 16B chunk (t&7)^(row&7)
    const int srow = t >> 3;
    const int scb = ((t & 7) ^ (srow & 7)) * 16;
    const unsigned char* gA = fb8 + (size_t)(i0 + srow) * DD + scb;
    const unsigned char* gB = fb8 + (size_t)(j0 + srow) * DD + scb;
    char* ldsA = sA + wid * 1024;  // wave-uniform base; HW adds lane*16
    char* ldsB = sB + wid * 1024;

    f32x4_t acc[4][4];
    const f32x4_t zz = {0.0f, 0.0f, 0.0f, 0.0f};
#pragma unroll
    for (int mi = 0; mi < 4; ++mi)
#pragma unroll
        for (int ni = 0; ni < 4; ++ni) acc[mi][ni] = zz;

    const int q = lane >> 4;
    const int mrow = lane & 15;
    const int x7 = lane & 7;
    const int c0 = ((q << 1) ^ x7) << 4;        // chunk byte offset, k-half 0
    const int c1 = (((q << 1) | 1) ^ x7) << 4;  // k-half 1

#pragma unroll 1
    for (int kb = 0; kb < 6; ++kb) {
        const int k0 = kb * 128;
#pragma unroll
        for (int i = 0; i < 4; ++i) {
            load_lds16(gA + (size_t)(i * 32) * DD + k0, ldsA + i * 4096);
            load_lds16(gB + (size_t)(i * 32) * DD + k0, ldsB + i * 4096);
        }
        __syncthreads();

        i32x8 af[4];
#pragma unroll
        for (int mi = 0; mi < 4; ++mi) {
            const char* p = sA + (wm * 64 + mi * 16 + mrow) * 128;
            i32x4 lo = *(const i32x4*)(p + c0);
            i32x4 hi = *(const i32x4*)(p + c1);
            af[mi] = __builtin_shufflevector(lo, hi, 0, 1, 2, 3, 4, 5, 6, 7);
        }
#pragma unroll
        for (int ni = 0; ni < 4; ++ni) {
            const char* p = sB + (wn * 64 + ni * 16 + mrow) * 128;
            i32x4 lo = *(const i32x4*)(p + c0);
            i32x4 hi = *(const i32x4*)(p + c1);
            i32x8 bf = __builtin_shufflevector(lo, hi, 0, 1, 2, 3, 4, 5, 6, 7);
#pragma unroll
            for (int mi = 0; mi < 4; ++mi)
                acc[mi][ni] = __builtin_amdgcn_mfma_scale_f32_16x16x128_f8f6f4(
                    af[mi], bf, acc[mi][ni], 0, 0,
                    0, 0x7F7F7F7F, 0, 0x7F7F7F7F);  // unit scales (E8M0=127)
        }
        __syncthreads();
    }

    // Epilogue. C/D layout: col=lane&15 (+ni*16), row=(lane>>4)*4+reg (+mi*16).
    const int colb = j0 + wn * 64 + mrow;
    const int rowb = i0 + wm * 64 + (q << 2);
    float cs[4] = {0.f, 0.f, 0.f, 0.f};
    float csn[4] = {0.f, 0.f, 0.f, 0.f};
#pragma unroll
    for (int mi = 0; mi < 4; ++mi) {
        float rsv[4] = {0.f, 0.f, 0.f, 0.f};
        float rsn[4] = {0.f, 0.f, 0.f, 0.f};
#pragma unroll
        for (int ni = 0; ni < 4; ++ni) {
            const int col = colb + ni * 16;
#pragma unroll
            for (int r = 0; r < 4; ++r) {
                const int row = rowb + mi * 16 + r;
                const float v = acc[mi][ni][r] * INV_T;
                float e = __expf(v - CMAX);
                if (isdiag && row == col) e = 0.0f;
                rsv[r] += e;
                cs[ni] += e;
                if (neardiag && (row / 3 == col / 3) && row != col) {
                    rsn[r] += e;
                    csn[ni] += e;
                }
            }
        }
#pragma unroll
        for (int r = 0; r < 4; ++r) {
            float v = rsv[r];
            v += __shfl_xor(v, 8);
            v += __shfl_xor(v, 4);
            v += __shfl_xor(v, 2);
            v += __shfl_xor(v, 1);
            if (mrow == 0) atomicAdd(&den_sum[rowb + mi * 16 + r], v);
        }
        if (neardiag) {
#pragma unroll
            for (int r = 0; r < 4; ++r) {
                float v = rsn[r];
                v += __shfl_xor(v, 8);
                v += __shfl_xor(v, 4);
                v += __shfl_xor(v, 2);
                v += __shfl_xor(v, 1);
                if (mrow == 0) atomicAdd(&num_sum[rowb + mi * 16 + r], v);
            }
        }
    }
    if (!isdiag) {
#pragma unroll
        for (int ni = 0; ni < 4; ++ni) {
            float v = cs[ni];
            v += __shfl_xor(v, 16);
            v += __shfl_xor(v, 32);
            if (q == 0) atomicAdd(&den_sum[colb + ni * 16], v);
        }
        if (neardiag) {
#pragma unroll
            for (int ni = 0; ni < 4; ++ni) {
                float v = csn[ni];
                v += __shfl_xor(v, 16);
                v += __shfl_xor(v, 32);
                if (q == 0) atomicAdd(&num_sum[colb + ni * 16], v);
            }
        }
    }

    // Last block computes the loss. threadfence-reduction pattern:
    // device fence, block barrier, counter RMW (acq_rel, agent);
    // last block reads den/num with agent-scope atomic loads (XCD-safe).
    __threadfence();
    __syncthreads();
    __shared__ int lastflag;
    if (t == 0) {
        const int prev = __hip_atomic_fetch_add(counter, 1, __ATOMIC_ACQ_REL,
                                                __HIP_MEMORY_SCOPE_AGENT);
        lastflag = (prev == NTILES - 1) ? 1 : 0;
    }
    __syncthreads();
    if (lastflag) {
        float local = 0.0f;
        for (int i = t; i < NN; i += 256) {
            const float d = __hip_atomic_load(&den_sum[i], __ATOMIC_RELAXED,
                                              __HIP_MEMORY_SCOPE_AGENT);
            const float n = __hip_atomic_load(&num_sum[i], __ATOMIC_RELAXED,
                                              __HIP_MEMORY_SCOPE_AGENT);
            local += logf(d) - logf(n);   // CMAX cancels in den-num
        }
#pragma unroll
        for (int m = 32; m >= 1; m >>= 1) local += __shfl_xor(local, m);
        __shared__ float wsum[4];
        if ((t & 63) == 0) wsum[t >> 6] = local;
        __syncthreads();
        if (t == 0) out[0] = (wsum[0] + wsum[1] + wsum[2] + wsum[3]) / (float)NN;
    }
}

extern "C" void kernel_launch(void* const* d_in, const int* in_sizes, int n_in,
                              void* d_out, int out_size, void* d_ws, size_t ws_size,
                              hipStream_t stream) {
    const float* feats = (const float*)d_in[0];
    float* out = (float*)d_out;

    char* ws = (char*)d_ws;
    unsigned int* fb8 = (unsigned int*)ws;                 // 6144*768 = 4718592 B
    float* den_num    = (float*)(ws + 4718592);            // 2*6144*4 + 4 B
    float* den_sum    = den_num;
    float* num_sum    = den_num + NN;
    int*   counter    = (int*)(den_num + 2 * NN);

    norm_kernel<<<NN / 4, 256, 0, stream>>>(feats, fb8, den_num);
    gemm_expsum_kernel<<<NTILES, 256, 0, stream>>>((const unsigned char*)fb8,
                                                   den_sum, num_sum, counter, out);
}

// Round 6
// 110.607 us; speedup vs baseline: 3.3050x; 1.6962x over previous
//
#include <hip/hip_runtime.h>

#define NN 6144
#define DD 768
#define NB 48               // 6144 / 128 tile blocks per dim
#define NTILES 1176         // NB*(NB+1)/2 upper-triangular tiles
#define INV_T 14.285714285714286f
#define CMAX  14.285714285714286f

typedef int i32x4 __attribute__((ext_vector_type(4)));
typedef int i32x8 __attribute__((ext_vector_type(8)));
typedef float f32x4_t __attribute__((ext_vector_type(4)));

__device__ __forceinline__ void load_lds16(const void* g, void* l) {
    __builtin_amdgcn_global_load_lds((__attribute__((address_space(1))) void*)g,
                                     (__attribute__((address_space(3))) void*)l,
                                     16, 0, 0);
}

// Kernel 1: L2-normalize rows -> fp8 e4m3 (unit MX scale); zero den/num sums.
// One wave per row; 1536 blocks x 256 threads.
__global__ void norm_kernel(const float* __restrict__ feats,
                            unsigned int* __restrict__ fb8,   // 6144*192 uints
                            float* __restrict__ den_num) {    // [0..NN)=den, [NN..2NN)=num
    const int wid = threadIdx.x >> 6;
    const int lane = threadIdx.x & 63;
    const int row = blockIdx.x * 4 + wid;

    if (threadIdx.x < 8) den_num[blockIdx.x * 8 + threadIdx.x] = 0.0f;

    const float4* src = (const float4*)(feats + (size_t)row * DD);
    float4 v[3];
    float ss = 0.0f;
#pragma unroll
    for (int i = 0; i < 3; ++i) {
        v[i] = src[lane + i * 64];
        ss += v[i].x * v[i].x + v[i].y * v[i].y + v[i].z * v[i].z + v[i].w * v[i].w;
    }
#pragma unroll
    for (int m = 32; m >= 1; m >>= 1) ss += __shfl_xor(ss, m);
    const float sc = 1.0f / fmaxf(sqrtf(ss), 1e-12f);

#pragma unroll
    for (int i = 0; i < 3; ++i) {
        unsigned int w = 0;
        w = __builtin_amdgcn_cvt_pk_fp8_f32(v[i].x * sc, v[i].y * sc, w, 0);
        w = __builtin_amdgcn_cvt_pk_fp8_f32(v[i].z * sc, v[i].w * sc, w, 1);
        fb8[(size_t)row * 192 + lane + i * 64] = w;
    }
}

// Kernel 2: upper-triangular MX-fp8 MFMA Gram tiles + fused exp row/col sums
// into den_sum (all) and num_sum (positive pairs).
// 1176 blocks (one 128x128 tile), 256 threads (2x2 waves of 64x64).
// __launch_bounds__(256,2) + #pragma unroll 1: avoids r3/r4's 185-344 MB
// scratch spill from full unroll of the 6-trip loop (VGPR_Count 64, clean).
// NO fences / NO scoped atomics here: r5's per-block __threadfence +
// acq_rel agent RMW (buffer_wbl2/buffer_inv L2 sweep per block) left all
// pipes idle (MfmaUtil 4.5%, VALU 7%, HBM 2.5%) at 128 us. Coherence for
// the finalize pass comes from the kernel-launch boundary instead.
__global__ __launch_bounds__(256, 2) void gemm_expsum_kernel(
        const unsigned char* __restrict__ fb8,
        float* __restrict__ den_sum, float* __restrict__ num_sum) {
    __shared__ __align__(16) char sA[128 * 128];
    __shared__ __align__(16) char sB[128 * 128];

    // triangular index -> (bi, bj), bi <= bj
    int rem = blockIdx.x;
    int bi = 0, rowlen = NB;
    while (rem >= rowlen) { rem -= rowlen; rowlen--; bi++; }
    const int bj = bi + rem;
    const bool isdiag = (bi == bj);
    const bool neardiag = (bj - bi) <= 1;
    const int i0 = bi * 128;
    const int j0 = bj * 128;

    const int t = threadIdx.x;
    const int lane = t & 63;
    const int wid = t >> 6;
    const int wm = wid >> 1;  // wave row (0..1)
    const int wn = wid & 1;   // wave col (0..1)

    // staging: thread t -> row = t>>3 (+32/issue), 16B chunk (t&7)^(row&7)
    const int srow = t >> 3;
    const int scb = ((t & 7) ^ (srow & 7)) * 16;
    const unsigned char* gA = fb8 + (size_t)(i0 + srow) * DD + scb;
    const unsigned char* gB = fb8 + (size_t)(j0 + srow) * DD + scb;
    char* ldsA = sA + wid * 1024;  // wave-uniform base; HW adds lane*16
    char* ldsB = sB + wid * 1024;

    f32x4_t acc[4][4];
    const f32x4_t zz = {0.0f, 0.0f, 0.0f, 0.0f};
#pragma unroll
    for (int mi = 0; mi < 4; ++mi)
#pragma unroll
        for (int ni = 0; ni < 4; ++ni) acc[mi][ni] = zz;

    const int q = lane >> 4;
    const int mrow = lane & 15;
    const int x7 = lane & 7;
    const int c0 = ((q << 1) ^ x7) << 4;        // chunk byte offset, k-half 0
    const int c1 = (((q << 1) | 1) ^ x7) << 4;  // k-half 1

#pragma unroll 1
    for (int kb = 0; kb < 6; ++kb) {
        const int k0 = kb * 128;
#pragma unroll
        for (int i = 0; i < 4; ++i) {
            load_lds16(gA + (size_t)(i * 32) * DD + k0, ldsA + i * 4096);
            load_lds16(gB + (size_t)(i * 32) * DD + k0, ldsB + i * 4096);
        }
        __syncthreads();

        i32x8 af[4];
#pragma unroll
        for (int mi = 0; mi < 4; ++mi) {
            const char* p = sA + (wm * 64 + mi * 16 + mrow) * 128;
            i32x4 lo = *(const i32x4*)(p + c0);
            i32x4 hi = *(const i32x4*)(p + c1);
            af[mi] = __builtin_shufflevector(lo, hi, 0, 1, 2, 3, 4, 5, 6, 7);
        }
#pragma unroll
        for (int ni = 0; ni < 4; ++ni) {
            const char* p = sB + (wn * 64 + ni * 16 + mrow) * 128;
            i32x4 lo = *(const i32x4*)(p + c0);
            i32x4 hi = *(const i32x4*)(p + c1);
            i32x8 bf = __builtin_shufflevector(lo, hi, 0, 1, 2, 3, 4, 5, 6, 7);
#pragma unroll
            for (int mi = 0; mi < 4; ++mi)
                acc[mi][ni] = __builtin_amdgcn_mfma_scale_f32_16x16x128_f8f6f4(
                    af[mi], bf, acc[mi][ni], 0, 0,
                    0, 0x7F7F7F7F, 0, 0x7F7F7F7F);  // unit scales (E8M0=127)
        }
        __syncthreads();
    }

    // Epilogue. C/D layout: col=lane&15 (+ni*16), row=(lane>>4)*4+reg (+mi*16).
    const int colb = j0 + wn * 64 + mrow;
    const int rowb = i0 + wm * 64 + (q << 2);
    float cs[4] = {0.f, 0.f, 0.f, 0.f};
    float csn[4] = {0.f, 0.f, 0.f, 0.f};
#pragma unroll
    for (int mi = 0; mi < 4; ++mi) {
        float rsv[4] = {0.f, 0.f, 0.f, 0.f};
        float rsn[4] = {0.f, 0.f, 0.f, 0.f};
#pragma unroll
        for (int ni = 0; ni < 4; ++ni) {
            const int col = colb + ni * 16;
#pragma unroll
            for (int r = 0; r < 4; ++r) {
                const int row = rowb + mi * 16 + r;
                const float v = acc[mi][ni][r] * INV_T;
                float e = __expf(v - CMAX);
                if (isdiag && row == col) e = 0.0f;
                rsv[r] += e;
                cs[ni] += e;
                if (neardiag && (row / 3 == col / 3) && row != col) {
                    rsn[r] += e;
                    csn[ni] += e;
                }
            }
        }
#pragma unroll
        for (int r = 0; r < 4; ++r) {
            float v = rsv[r];
            v += __shfl_xor(v, 8);
            v += __shfl_xor(v, 4);
            v += __shfl_xor(v, 2);
            v += __shfl_xor(v, 1);
            if (mrow == 0) atomicAdd(&den_sum[rowb + mi * 16 + r], v);
        }
        if (neardiag) {
#pragma unroll
            for (int r = 0; r < 4; ++r) {
                float v = rsn[r];
                v += __shfl_xor(v, 8);
                v += __shfl_xor(v, 4);
                v += __shfl_xor(v, 2);
                v += __shfl_xor(v, 1);
                if (mrow == 0) atomicAdd(&num_sum[rowb + mi * 16 + r], v);
            }
        }
    }
    if (!isdiag) {
#pragma unroll
        for (int ni = 0; ni < 4; ++ni) {
            float v = cs[ni];
            v += __shfl_xor(v, 16);
            v += __shfl_xor(v, 32);
            if (q == 0) atomicAdd(&den_sum[colb + ni * 16], v);
        }
        if (neardiag) {
#pragma unroll
            for (int ni = 0; ni < 4; ++ni) {
                float v = csn[ni];
                v += __shfl_xor(v, 16);
                v += __shfl_xor(v, 32);
                if (q == 0) atomicAdd(&num_sum[colb + ni * 16], v);
            }
        }
    }
}

// Kernel 3: loss = mean(log(den) - log(num))  (CMAX cancels). Single block.
__global__ void finalize_kernel(const float* __restrict__ den_sum,
                                const float* __restrict__ num_sum,
                                float* __restrict__ out) {
    float local = 0.0f;
    for (int i = threadIdx.x; i < NN; i += 256) {
        local += logf(den_sum[i]) - logf(num_sum[i]);
    }
#pragma unroll
    for (int m = 32; m >= 1; m >>= 1) local += __shfl_xor(local, m);
    __shared__ float ws[4];
    if ((threadIdx.x & 63) == 0) ws[threadIdx.x >> 6] = local;
    __syncthreads();
    if (threadIdx.x == 0) out[0] = (ws[0] + ws[1] + ws[2] + ws[3]) / (float)NN;
}

extern "C" void kernel_launch(void* const* d_in, const int* in_sizes, int n_in,
                              void* d_out, int out_size, void* d_ws, size_t ws_size,
                              hipStream_t stream) {
    const float* feats = (const float*)d_in[0];
    float* out = (float*)d_out;

    char* ws = (char*)d_ws;
    unsigned int* fb8 = (unsigned int*)ws;                 // 6144*768 = 4718592 B
    float* den_num    = (float*)(ws + 4718592);            // 2*6144*4 B
    float* den_sum    = den_num;
    float* num_sum    = den_num + NN;

    norm_kernel<<<NN / 4, 256, 0, stream>>>(feats, fb8, den_num);
    gemm_expsum_kernel<<<NTILES, 256, 0, stream>>>((const unsigned char*)fb8,
                                                   den_sum, num_sum);
    finalize_kernel<<<1, 256, 0, stream>>>(den_sum, num_sum, out);
}